// Round 12
// baseline (81.171 us; speedup 1.0000x reference)
//
#include <hip/hip_runtime.h>

#define HWSZ 6400          // 80*80
#define PP   96            // padded plane dim (y,x in [-8,87])
#define PLANE (PP*PP*128)  // elems per padded plane (1,179,648; 2,359,296 B)

typedef short bf16x8 __attribute__((ext_vector_type(8)));
typedef float f32x4  __attribute__((ext_vector_type(4)));
typedef float f32x2  __attribute__((ext_vector_type(2)));
typedef uint  u32x4  __attribute__((ext_vector_type(4)));

__device__ inline ushort f2bf(float f) {
    uint u = __float_as_uint(f);
    u += 0x7fffu + ((u >> 16) & 1u);     // RNE
    return (ushort)(u >> 16);
}

// ---------------------------------------------------------------------------
// prep: fragment-major bf16 weights.
//   wA   [ot 0..7][S 0..35][lane 0..63][j 0..7]  (main conv, o = ot*16+(lane&15))
//   wAoff[ot 0..1][S 0..35][lane 0..63][j 0..7]  (offset conv, rows >=18 zero)
//   K = S*32 + 8*(lane>>4) + j ; tap k = K>>7 ; c = K&127  (tap-major K)
// ---------------------------------------------------------------------------
__global__ __launch_bounds__(256) void prep_weights(const float* __restrict__ w,
                                                    const float* __restrict__ w_off,
                                                    ushort* __restrict__ wA,
                                                    ushort* __restrict__ wAoff) {
    int idx = blockIdx.x * 256 + threadIdx.x;
    if (idx < 147456) {
        int ot = idx / 18432, rem = idx - ot * 18432;
        int s = rem >> 9, lane = (rem >> 3) & 63, j = rem & 7;
        int o = ot * 16 + (lane & 15);
        int K = s * 32 + 8 * (lane >> 4) + j;
        int k = K >> 7, c = K & 127;
        wA[idx] = f2bf(w[(o * 128 + c) * 9 + k]);
    } else if (idx < 147456 + 36864) {
        int i = idx - 147456;
        int ot = i / 18432, rem = i - ot * 18432;
        int s = rem >> 9, lane = (rem >> 3) & 63, j = rem & 7;
        int o = ot * 16 + (lane & 15);
        int K = s * 32 + 8 * (lane >> 4) + j;
        int k = K >> 7, c = K & 127;
        wAoff[i] = (o < 18) ? f2bf(w_off[(o * 128 + c) * 9 + k]) : (ushort)0;
    }
}

// ---------------------------------------------------------------------------
// transpose x -> padded NHWC bf16 plane g, WRITING the zero borders too
// (replaces the 18.9 MB memset).  grid (96 padded rows, G), block 256.
// ---------------------------------------------------------------------------
__global__ __launch_bounds__(256) void transpose_x(const float* __restrict__ x,
                                                   ushort* __restrict__ xTp,
                                                   int n_base) {
    __shared__ ushort st[80 * 136];      // [w][c]; 136 -> 16B-aligned rows
    int hp = blockIdx.x, g = blockIdx.y; // hp = padded row 0..95
    int t = threadIdx.x;
    const bool interior = (hp >= 8) && (hp < 88);
    if (interior) {
        int h = hp - 8;
        const float* xn = x + ((size_t)(n_base + g) * 128) * HWSZ + h * 80;
        for (int i = 0; i < 40; ++i) {
            int e = t + i * 256;         // e = c*80 + w   (10240 total)
            int c = e / 80;
            int wcol = e - c * 80;
            st[wcol * 136 + c] = f2bf(xn[(size_t)c * HWSZ + wcol]);
        }
        __syncthreads();
    }
    ushort* dst = xTp + (size_t)g * PLANE + (size_t)hp * PP * 128;
    for (int i = 0; i < 6; ++i) {
        int e = t + i * 256;             // 1536 x 16B units: col*16 + cq
        int col = e >> 4, cq = e & 15;
        u32x4 v = {0u, 0u, 0u, 0u};
        if (interior && col >= 8 && col < 88)
            v = *(const u32x4*)(st + (col - 8) * 136 + cq * 8);
        *(u32x4*)(dst + (size_t)col * 128 + cq * 8) = v;
    }
}

// ---------------------------------------------------------------------------
// offset conv as MFMA im2col GEMM.  Tile 4x16 px, 4 waves (one px-row each).
// grid (5, 20, G), block 256.  Plane g -> offs[g].
// ---------------------------------------------------------------------------
__global__ __launch_bounds__(256) void offset_mfma(const ushort* __restrict__ xTp,
                                                   const ushort* __restrict__ wAoff,
                                                   const float* __restrict__ b_off,
                                                   float* __restrict__ offs) {
    __shared__ ushort xs[6 * 18 * 136];  // 29376 B
    int t = threadIdx.x;
    int w0 = blockIdx.x * 16, h0 = blockIdx.y * 4, g = blockIdx.z;
    const ushort* xb = xTp + (size_t)g * PLANE + ((size_t)(h0 + 7) * PP + (w0 + 7)) * 128;
    for (int i = 0; i < 7; ++i) {
        int e = t + i * 256;
        if (e < 1728) {                  // 6 rows x 18 cols x 16 cq
            int r = e / 288, rem = e - r * 288;
            int col = rem >> 4, cq = rem & 15;
            u32x4 v = *(const u32x4*)(xb + ((size_t)r * PP + col) * 128 + cq * 8);
            *(u32x4*)(xs + (r * 18 + col) * 136 + cq * 8) = v;
        }
    }
    __syncthreads();
    int lane = t & 63, wv = t >> 6;
    f32x4 acc0 = {0.f, 0.f, 0.f, 0.f};
    f32x4 acc1 = {0.f, 0.f, 0.f, 0.f};
    #pragma unroll
    for (int k = 0; k < 9; ++k) {
        int ky = k / 3, kx = k - ky * 3;
        #pragma unroll
        for (int q = 0; q < 4; ++q) {
            int s = k * 4 + q;
            bf16x8 a0 = *(const bf16x8*)(wAoff + ((size_t)(0 * 36 + s) * 64 + lane) * 8);
            bf16x8 a1 = *(const bf16x8*)(wAoff + ((size_t)(1 * 36 + s) * 64 + lane) * 8);
            bf16x8 bb = *(const bf16x8*)(xs + ((wv + ky) * 18 + (lane & 15) + kx) * 136
                                          + q * 32 + 8 * (lane >> 4));
            acc0 = __builtin_amdgcn_mfma_f32_16x16x32_bf16(a0, bb, acc0, 0, 0, 0);
            acc1 = __builtin_amdgcn_mfma_f32_16x16x32_bf16(a1, bb, acc1, 0, 0, 0);
        }
    }
    int col = lane & 15, rg = lane >> 4;
    int prow = h0 + wv, pcol = w0 + col;
    #pragma unroll
    for (int r = 0; r < 4; ++r) {
        int oc = rg * 4 + r;
        offs[((size_t)(g * 18 + oc)) * HWSZ + prow * 80 + pcol] = acc0[r] + b_off[oc];
    }
    if (rg == 0) {
        #pragma unroll
        for (int r = 0; r < 2; ++r) {
            int oc = 16 + r;
            offs[((size_t)(g * 18 + oc)) * HWSZ + prow * 80 + pcol] = acc1[r] + b_off[oc];
        }
    }
}

// ---------------------------------------------------------------------------
// deformable conv: 2x16 px tile, K=1152 in 3 chunks of (3 taps x 128 ch).
//   v_lds rows (per pixel) 768 B, XOR-swizzled: byte ^= (p&7)<<4 on BOTH the
//   gather write and the MFMA fragment read (same involution, rule #21).
//   Gather math in packed f32 pairs + v_cvt_pk_bf16_f32.
// grid (5, 40, G), block 256 (4 waves x 32 o).
// ---------------------------------------------------------------------------
__global__ __launch_bounds__(256) void deform_gemm(const ushort* __restrict__ xTp,
                                                   const float* __restrict__ offs,
                                                   const ushort* __restrict__ wA,
                                                   const float* __restrict__ b,
                                                   float* __restrict__ out,
                                                   int n_base) {
    __shared__ ushort v_lds[32 * 384];   // 24576 B (swizzled)
    __shared__ int setup[288 * 8];       // 9216 B

    int t = threadIdx.x;
    int w0 = blockIdx.x * 16, h0 = blockIdx.y * 2, g = blockIdx.z;
    const ushort* xn = xTp + (size_t)g * PLANE;

    // ---- Phase 0: per-(tap,pixel) bilinear setup ----
    #pragma unroll
    for (int s = 0; s < 2; ++s) {
        int pair = t + s * 256;
        if (pair < 288) {
            int k = pair >> 5, p = pair & 31;
            int hh = h0 + (p >> 4), ww = w0 + (p & 15);
            size_t ob = ((size_t)(g * 18 + 2 * k)) * HWSZ + hh * 80 + ww;
            float dy = offs[ob], dx = offs[ob + HWSZ];
            int ky = k / 3, kx = k - ky * 3;
            float py = fminf(fmaxf((float)(hh + ky - 1) + dy, -7.5f), 86.5f);
            float px = fminf(fmaxf((float)(ww + kx - 1) + dx, -7.5f), 86.5f);
            float y0f = floorf(py), x0f = floorf(px);
            float fy = py - y0f, fx = px - x0f;
            int y0 = (int)y0f + 8, x0 = (int)x0f + 8;   // in [0,94]
            int rb0 = (y0 * PP + x0) * 128;
            setup[pair * 8 + 0] = rb0;
            setup[pair * 8 + 1] = rb0 + PP * 128;
            ((float*)setup)[pair * 8 + 2] = (1.f - fy) * (1.f - fx);
            ((float*)setup)[pair * 8 + 3] = (1.f - fy) * fx;
            ((float*)setup)[pair * 8 + 4] = fy * (1.f - fx);
            ((float*)setup)[pair * 8 + 5] = fy * fx;
        }
    }
    __syncthreads();

    int lane = t & 63;
    int o_t = (t >> 6) * 2;
    f32x4 acc[2][2];
    #pragma unroll
    for (int oi = 0; oi < 2; ++oi)
        #pragma unroll
        for (int pj = 0; pj < 2; ++pj) {
            f32x4 z = {0.f, 0.f, 0.f, 0.f};
            acc[oi][pj] = z;
        }

    const int m  = lane & 15;            // fragment row (pixel 0..15)
    const int q16 = (lane >> 4) * 16;    // k-subgroup byte offset
    const int xorc = (m & 7) << 4;       // read-side swizzle constant

    for (int cc = 0; cc < 3; ++cc) {
        if (cc) __syncthreads();
        // ---- gather: 6 units/thread; packed-f32 bilinear; swizzled write ----
        #pragma unroll
        for (int j = 0; j < 6; ++j) {
            int u = t + j * 256;
            int cg = u & 15;             // channel-group (8 ch)
            int pr = u >> 4;             // 0..95
            int tr = pr >> 5;            // tap within chunk
            int p  = pr & 31;            // pixel
            int pair = (cc * 3 + tr) * 32 + p;
            const int* su = &setup[pair * 8];
            int rb0 = su[0], rb1 = su[1];
            float w00 = ((const float*)su)[2], w01 = ((const float*)su)[3];
            float w10 = ((const float*)su)[4], w11 = ((const float*)su)[5];
            f32x2 W00 = {w00, w00}, W01 = {w01, w01};
            f32x2 W10 = {w10, w10}, W11 = {w11, w11};
            const ushort* p0 = xn + rb0 + cg * 8;
            const ushort* p1 = xn + rb1 + cg * 8;
            u32x4 g00 = *(const u32x4*)p0;
            u32x4 g01 = *(const u32x4*)(p0 + 128);
            u32x4 g10 = *(const u32x4*)p1;
            u32x4 g11 = *(const u32x4*)(p1 + 128);
            uint rr[4];
            #pragma unroll
            for (int c2 = 0; c2 < 4; ++c2) {
                f32x2 a00 = {__uint_as_float(g00[c2] << 16),
                             __uint_as_float(g00[c2] & 0xffff0000u)};
                f32x2 a01 = {__uint_as_float(g01[c2] << 16),
                             __uint_as_float(g01[c2] & 0xffff0000u)};
                f32x2 a10 = {__uint_as_float(g10[c2] << 16),
                             __uint_as_float(g10[c2] & 0xffff0000u)};
                f32x2 a11 = {__uint_as_float(g11[c2] << 16),
                             __uint_as_float(g11[c2] & 0xffff0000u)};
                f32x2 av = a00 * W00;
                av = __builtin_elementwise_fma(a01, W01, av);
                av = __builtin_elementwise_fma(a10, W10, av);
                av = __builtin_elementwise_fma(a11, W11, av);
                uint pk;
                asm("v_cvt_pk_bf16_f32 %0, %1, %2" : "=v"(pk) : "v"(av[0]), "v"(av[1]));
                rr[c2] = pk;
            }
            u32x4 rv = {rr[0], rr[1], rr[2], rr[3]};
            int wb = p * 768 + ((tr * 256 + cg * 16) ^ ((p & 7) << 4));
            *(u32x4*)((char*)v_lds + wb) = rv;
        }
        __syncthreads();
        // ---- MFMA: 12 K-steps (3 taps x 128 ch), swizzled b128 reads ----
        #pragma unroll
        for (int s = 0; s < 12; ++s) {
            int S = cc * 12 + s;
            bf16x8 a0 = *(const bf16x8*)(wA + ((size_t)(o_t * 36 + S) * 64 + lane) * 8);
            bf16x8 a1 = *(const bf16x8*)(wA + ((size_t)((o_t + 1) * 36 + S) * 64 + lane) * 8);
            int rb = m * 768 + ((s * 64 + q16) ^ xorc);
            bf16x8 b0 = *(const bf16x8*)((const char*)v_lds + rb);
            bf16x8 b1 = *(const bf16x8*)((const char*)v_lds + rb + 16 * 768);
            acc[0][0] = __builtin_amdgcn_mfma_f32_16x16x32_bf16(a0, b0, acc[0][0], 0, 0, 0);
            acc[0][1] = __builtin_amdgcn_mfma_f32_16x16x32_bf16(a0, b1, acc[0][1], 0, 0, 0);
            acc[1][0] = __builtin_amdgcn_mfma_f32_16x16x32_bf16(a1, b0, acc[1][0], 0, 0, 0);
            acc[1][1] = __builtin_amdgcn_mfma_f32_16x16x32_bf16(a1, b1, acc[1][1], 0, 0, 0);
        }
    }

    // ---- epilogue: bias + store ----
    int o_w = (t >> 6) * 32;
    int n = n_base + g;
    #pragma unroll
    for (int oi = 0; oi < 2; ++oi)
        #pragma unroll
        for (int pj = 0; pj < 2; ++pj)
            #pragma unroll
            for (int r = 0; r < 4; ++r) {
                int o = o_w + oi * 16 + (lane >> 4) * 4 + r;
                int col = lane & 15;
                out[((size_t)(n * 128 + o)) * HWSZ + (h0 + pj) * 80 + w0 + col]
                    = acc[oi][pj][r] + b[o];
            }
}

// ---------------------------------------------------------------------------
extern "C" void kernel_launch(void* const* d_in, const int* in_sizes, int n_in,
                              void* d_out, int out_size, void* d_ws, size_t ws_size,
                              hipStream_t stream) {
    const float* x     = (const float*)d_in[0];   // (8,128,80,80)
    const float* w_off = (const float*)d_in[1];   // (18,128,3,3)
    const float* b_off = (const float*)d_in[2];   // (18,)
    const float* wmain = (const float*)d_in[3];   // (128,128,3,3)
    const float* bias  = (const float*)d_in[4];   // (128,)
    float* out = (float*)d_out;                   // (8,128,80,80)

    const size_t offsB_full = 8u * 18u * HWSZ * 4u;        // 3,686,400
    const size_t planeB     = (size_t)PLANE * 2u;          // 2,359,296
    const bool big = ws_size >= (offsB_full + 8 * planeB + 294912 + 73728);

    if (big) {
        // single-pass layout: offs | planes(8) | wA | wAoff  (22.93 MB)
        float*  offs  = (float*)d_ws;
        ushort* xTp   = (ushort*)((char*)d_ws + offsB_full);
        ushort* wA    = (ushort*)((char*)xTp + 8 * planeB);
        ushort* wAoff = (ushort*)((char*)wA + 294912);

        prep_weights<<<720, 256, 0, stream>>>(wmain, w_off, wA, wAoff);
        transpose_x<<<dim3(96, 8), 256, 0, stream>>>(x, xTp, 0);
        offset_mfma<<<dim3(5, 20, 8), 256, 0, stream>>>(xTp, wAoff, b_off, offs);
        deform_gemm<<<dim3(5, 40, 8), 256, 0, stream>>>(xTp, offs, wA, bias, out, 0);
    } else {
        // per-n layout: plane(1) | offs(1) | wA | wAoff  (3.19 MB)
        ushort* xTp   = (ushort*)d_ws;
        float*  offs  = (float*)((char*)d_ws + planeB);
        ushort* wA    = (ushort*)((char*)offs + 18u * HWSZ * 4u);
        ushort* wAoff = (ushort*)((char*)wA + 294912);

        prep_weights<<<720, 256, 0, stream>>>(wmain, w_off, wA, wAoff);
        for (int n = 0; n < 8; ++n) {
            transpose_x<<<dim3(96, 1), 256, 0, stream>>>(x, xTp, n);
            offset_mfma<<<dim3(5, 20, 1), 256, 0, stream>>>(xTp, wAoff, b_off, offs);
            deform_gemm<<<dim3(5, 40, 1), 256, 0, stream>>>(xTp, offs, wA, bias, out, n);
        }
    }
}

// Round 13
// 74.394 us; speedup vs baseline: 1.0911x; 1.0911x over previous
//
#include <hip/hip_runtime.h>

#define HWSZ 6400          // 80*80
#define PP   96            // padded plane dim (y,x in [-8,87])
#define PLANE (PP*PP*128)  // elems per padded plane (1,179,648; 2,359,296 B)

typedef short bf16x8 __attribute__((ext_vector_type(8)));
typedef float f32x4  __attribute__((ext_vector_type(4)));
typedef float f32x2  __attribute__((ext_vector_type(2)));
typedef uint  u32x4  __attribute__((ext_vector_type(4)));

__device__ inline ushort f2bf(float f) {
    uint u = __float_as_uint(f);
    u += 0x7fffu + ((u >> 16) & 1u);     // RNE
    return (ushort)(u >> 16);
}

// ---------------------------------------------------------------------------
// prep: fragment-major bf16 weights.
//   wA   [ot 0..7][S 0..35][lane 0..63][j 0..7]  (main conv, o = ot*16+(lane&15))
//   wAoff[ot 0..1][S 0..35][lane 0..63][j 0..7]  (offset conv, rows >=18 zero)
//   K = S*32 + 8*(lane>>4) + j ; tap k = K>>7 ; c = K&127  (tap-major K)
// ---------------------------------------------------------------------------
__global__ __launch_bounds__(256) void prep_weights(const float* __restrict__ w,
                                                    const float* __restrict__ w_off,
                                                    ushort* __restrict__ wA,
                                                    ushort* __restrict__ wAoff) {
    int idx = blockIdx.x * 256 + threadIdx.x;
    if (idx < 147456) {
        int ot = idx / 18432, rem = idx - ot * 18432;
        int s = rem >> 9, lane = (rem >> 3) & 63, j = rem & 7;
        int o = ot * 16 + (lane & 15);
        int K = s * 32 + 8 * (lane >> 4) + j;
        int k = K >> 7, c = K & 127;
        wA[idx] = f2bf(w[(o * 128 + c) * 9 + k]);
    } else if (idx < 147456 + 36864) {
        int i = idx - 147456;
        int ot = i / 18432, rem = i - ot * 18432;
        int s = rem >> 9, lane = (rem >> 3) & 63, j = rem & 7;
        int o = ot * 16 + (lane & 15);
        int K = s * 32 + 8 * (lane >> 4) + j;
        int k = K >> 7, c = K & 127;
        wAoff[i] = (o < 18) ? f2bf(w_off[(o * 128 + c) * 9 + k]) : (ushort)0;
    }
}

// ---------------------------------------------------------------------------
// transpose x -> padded NHWC bf16 plane g, WRITING the zero borders too.
// grid (G, 96): g = blockIdx.x (fastest -> XCD affinity), hp = blockIdx.y.
// ---------------------------------------------------------------------------
__global__ __launch_bounds__(256) void transpose_x(const float* __restrict__ x,
                                                   ushort* __restrict__ xTp,
                                                   int n_base) {
    __shared__ ushort st[80 * 136];      // [w][c]; 136 -> 16B-aligned rows
    int g = blockIdx.x, hp = blockIdx.y; // hp = padded row 0..95
    int t = threadIdx.x;
    const bool interior = (hp >= 8) && (hp < 88);
    if (interior) {
        int h = hp - 8;
        const float* xn = x + ((size_t)(n_base + g) * 128) * HWSZ + h * 80;
        for (int i = 0; i < 40; ++i) {
            int e = t + i * 256;         // e = c*80 + w   (10240 total)
            int c = e / 80;
            int wcol = e - c * 80;
            st[wcol * 136 + c] = f2bf(xn[(size_t)c * HWSZ + wcol]);
        }
        __syncthreads();
    }
    ushort* dst = xTp + (size_t)g * PLANE + (size_t)hp * PP * 128;
    for (int i = 0; i < 6; ++i) {
        int e = t + i * 256;             // 1536 x 16B units: col*16 + cq
        int col = e >> 4, cq = e & 15;
        u32x4 v = {0u, 0u, 0u, 0u};
        if (interior && col >= 8 && col < 88)
            v = *(const u32x4*)(st + (col - 8) * 136 + cq * 8);
        *(u32x4*)(dst + (size_t)col * 128 + cq * 8) = v;
    }
}

// ---------------------------------------------------------------------------
// offset conv as MFMA im2col GEMM.  Tile 4x16 px, 4 waves (one px-row each).
// grid (G, 5, 20): g = blockIdx.x (XCD affinity), w0/h0 from y/z.
// ---------------------------------------------------------------------------
__global__ __launch_bounds__(256) void offset_mfma(const ushort* __restrict__ xTp,
                                                   const ushort* __restrict__ wAoff,
                                                   const float* __restrict__ b_off,
                                                   float* __restrict__ offs) {
    __shared__ ushort xs[6 * 18 * 136];  // 29376 B
    int t = threadIdx.x;
    int g = blockIdx.x;
    int w0 = blockIdx.y * 16, h0 = blockIdx.z * 4;
    const ushort* xb = xTp + (size_t)g * PLANE + ((size_t)(h0 + 7) * PP + (w0 + 7)) * 128;
    for (int i = 0; i < 7; ++i) {
        int e = t + i * 256;
        if (e < 1728) {                  // 6 rows x 18 cols x 16 cq
            int r = e / 288, rem = e - r * 288;
            int col = rem >> 4, cq = rem & 15;
            u32x4 v = *(const u32x4*)(xb + ((size_t)r * PP + col) * 128 + cq * 8);
            *(u32x4*)(xs + (r * 18 + col) * 136 + cq * 8) = v;
        }
    }
    __syncthreads();
    int lane = t & 63, wv = t >> 6;
    f32x4 acc0 = {0.f, 0.f, 0.f, 0.f};
    f32x4 acc1 = {0.f, 0.f, 0.f, 0.f};
    #pragma unroll
    for (int k = 0; k < 9; ++k) {
        int ky = k / 3, kx = k - ky * 3;
        #pragma unroll
        for (int q = 0; q < 4; ++q) {
            int s = k * 4 + q;
            bf16x8 a0 = *(const bf16x8*)(wAoff + ((size_t)(0 * 36 + s) * 64 + lane) * 8);
            bf16x8 a1 = *(const bf16x8*)(wAoff + ((size_t)(1 * 36 + s) * 64 + lane) * 8);
            bf16x8 bb = *(const bf16x8*)(xs + ((wv + ky) * 18 + (lane & 15) + kx) * 136
                                          + q * 32 + 8 * (lane >> 4));
            acc0 = __builtin_amdgcn_mfma_f32_16x16x32_bf16(a0, bb, acc0, 0, 0, 0);
            acc1 = __builtin_amdgcn_mfma_f32_16x16x32_bf16(a1, bb, acc1, 0, 0, 0);
        }
    }
    int col = lane & 15, rg = lane >> 4;
    int prow = h0 + wv, pcol = w0 + col;
    #pragma unroll
    for (int r = 0; r < 4; ++r) {
        int oc = rg * 4 + r;
        offs[((size_t)(g * 18 + oc)) * HWSZ + prow * 80 + pcol] = acc0[r] + b_off[oc];
    }
    if (rg == 0) {
        #pragma unroll
        for (int r = 0; r < 2; ++r) {
            int oc = 16 + r;
            offs[((size_t)(g * 18 + oc)) * HWSZ + prow * 80 + pcol] = acc1[r] + b_off[oc];
        }
    }
}

// ---------------------------------------------------------------------------
// deformable conv: 2x16 px tile, K=1152 in 3 chunks of (3 taps x 128 ch).
//   Body identical to the passing r6/r10/r12 kernel; ONLY the blockIdx
//   component assignment changed: g = blockIdx.x (XCD affinity), w0/h0 from y/z.
// grid (G, 5, 40), block 256 (4 waves x 32 o).
// ---------------------------------------------------------------------------
__global__ __launch_bounds__(256) void deform_gemm(const ushort* __restrict__ xTp,
                                                   const float* __restrict__ offs,
                                                   const ushort* __restrict__ wA,
                                                   const float* __restrict__ b,
                                                   float* __restrict__ out,
                                                   int n_base) {
    __shared__ ushort v_lds[32 * 384];   // 24576 B (swizzled)
    __shared__ int setup[288 * 8];       // 9216 B

    int t = threadIdx.x;
    int g = blockIdx.x;
    int w0 = blockIdx.y * 16, h0 = blockIdx.z * 2;
    const ushort* xn = xTp + (size_t)g * PLANE;

    // ---- Phase 0: per-(tap,pixel) bilinear setup ----
    #pragma unroll
    for (int s = 0; s < 2; ++s) {
        int pair = t + s * 256;
        if (pair < 288) {
            int k = pair >> 5, p = pair & 31;
            int hh = h0 + (p >> 4), ww = w0 + (p & 15);
            size_t ob = ((size_t)(g * 18 + 2 * k)) * HWSZ + hh * 80 + ww;
            float dy = offs[ob], dx = offs[ob + HWSZ];
            int ky = k / 3, kx = k - ky * 3;
            float py = fminf(fmaxf((float)(hh + ky - 1) + dy, -7.5f), 86.5f);
            float px = fminf(fmaxf((float)(ww + kx - 1) + dx, -7.5f), 86.5f);
            float y0f = floorf(py), x0f = floorf(px);
            float fy = py - y0f, fx = px - x0f;
            int y0 = (int)y0f + 8, x0 = (int)x0f + 8;   // in [0,94]
            int rb0 = (y0 * PP + x0) * 128;
            setup[pair * 8 + 0] = rb0;
            setup[pair * 8 + 1] = rb0 + PP * 128;
            ((float*)setup)[pair * 8 + 2] = (1.f - fy) * (1.f - fx);
            ((float*)setup)[pair * 8 + 3] = (1.f - fy) * fx;
            ((float*)setup)[pair * 8 + 4] = fy * (1.f - fx);
            ((float*)setup)[pair * 8 + 5] = fy * fx;
        }
    }
    __syncthreads();

    int lane = t & 63;
    int o_t = (t >> 6) * 2;
    f32x4 acc[2][2];
    #pragma unroll
    for (int oi = 0; oi < 2; ++oi)
        #pragma unroll
        for (int pj = 0; pj < 2; ++pj) {
            f32x4 z = {0.f, 0.f, 0.f, 0.f};
            acc[oi][pj] = z;
        }

    const int m  = lane & 15;            // fragment row (pixel 0..15)
    const int q16 = (lane >> 4) * 16;    // k-subgroup byte offset
    const int xorc = (m & 7) << 4;       // read-side swizzle constant

    for (int cc = 0; cc < 3; ++cc) {
        if (cc) __syncthreads();
        // ---- gather: 6 units/thread; packed-f32 bilinear; swizzled write ----
        #pragma unroll
        for (int j = 0; j < 6; ++j) {
            int u = t + j * 256;
            int cg = u & 15;             // channel-group (8 ch)
            int pr = u >> 4;             // 0..95
            int tr = pr >> 5;            // tap within chunk
            int p  = pr & 31;            // pixel
            int pair = (cc * 3 + tr) * 32 + p;
            const int* su = &setup[pair * 8];
            int rb0 = su[0], rb1 = su[1];
            float w00 = ((const float*)su)[2], w01 = ((const float*)su)[3];
            float w10 = ((const float*)su)[4], w11 = ((const float*)su)[5];
            f32x2 W00 = {w00, w00}, W01 = {w01, w01};
            f32x2 W10 = {w10, w10}, W11 = {w11, w11};
            const ushort* p0 = xn + rb0 + cg * 8;
            const ushort* p1 = xn + rb1 + cg * 8;
            u32x4 g00 = *(const u32x4*)p0;
            u32x4 g01 = *(const u32x4*)(p0 + 128);
            u32x4 g10 = *(const u32x4*)p1;
            u32x4 g11 = *(const u32x4*)(p1 + 128);
            uint rr[4];
            #pragma unroll
            for (int c2 = 0; c2 < 4; ++c2) {
                f32x2 a00 = {__uint_as_float(g00[c2] << 16),
                             __uint_as_float(g00[c2] & 0xffff0000u)};
                f32x2 a01 = {__uint_as_float(g01[c2] << 16),
                             __uint_as_float(g01[c2] & 0xffff0000u)};
                f32x2 a10 = {__uint_as_float(g10[c2] << 16),
                             __uint_as_float(g10[c2] & 0xffff0000u)};
                f32x2 a11 = {__uint_as_float(g11[c2] << 16),
                             __uint_as_float(g11[c2] & 0xffff0000u)};
                f32x2 av = a00 * W00;
                av = __builtin_elementwise_fma(a01, W01, av);
                av = __builtin_elementwise_fma(a10, W10, av);
                av = __builtin_elementwise_fma(a11, W11, av);
                uint pk;
                asm("v_cvt_pk_bf16_f32 %0, %1, %2" : "=v"(pk) : "v"(av[0]), "v"(av[1]));
                rr[c2] = pk;
            }
            u32x4 rv = {rr[0], rr[1], rr[2], rr[3]};
            int wb = p * 768 + ((tr * 256 + cg * 16) ^ ((p & 7) << 4));
            *(u32x4*)((char*)v_lds + wb) = rv;
        }
        __syncthreads();
        // ---- MFMA: 12 K-steps (3 taps x 128 ch), swizzled b128 reads ----
        #pragma unroll
        for (int s = 0; s < 12; ++s) {
            int S = cc * 12 + s;
            bf16x8 a0 = *(const bf16x8*)(wA + ((size_t)(o_t * 36 + S) * 64 + lane) * 8);
            bf16x8 a1 = *(const bf16x8*)(wA + ((size_t)((o_t + 1) * 36 + S) * 64 + lane) * 8);
            int rb = m * 768 + ((s * 64 + q16) ^ xorc);
            bf16x8 b0 = *(const bf16x8*)((const char*)v_lds + rb);
            bf16x8 b1 = *(const bf16x8*)((const char*)v_lds + rb + 16 * 768);
            acc[0][0] = __builtin_amdgcn_mfma_f32_16x16x32_bf16(a0, b0, acc[0][0], 0, 0, 0);
            acc[0][1] = __builtin_amdgcn_mfma_f32_16x16x32_bf16(a0, b1, acc[0][1], 0, 0, 0);
            acc[1][0] = __builtin_amdgcn_mfma_f32_16x16x32_bf16(a1, b0, acc[1][0], 0, 0, 0);
            acc[1][1] = __builtin_amdgcn_mfma_f32_16x16x32_bf16(a1, b1, acc[1][1], 0, 0, 0);
        }
    }

    // ---- epilogue: bias + store ----
    int o_w = (t >> 6) * 32;
    int n = n_base + g;
    #pragma unroll
    for (int oi = 0; oi < 2; ++oi)
        #pragma unroll
        for (int pj = 0; pj < 2; ++pj)
            #pragma unroll
            for (int r = 0; r < 4; ++r) {
                int o = o_w + oi * 16 + (lane >> 4) * 4 + r;
                int col = lane & 15;
                out[((size_t)(n * 128 + o)) * HWSZ + (h0 + pj) * 80 + w0 + col]
                    = acc[oi][pj][r] + b[o];
            }
}

// ---------------------------------------------------------------------------
extern "C" void kernel_launch(void* const* d_in, const int* in_sizes, int n_in,
                              void* d_out, int out_size, void* d_ws, size_t ws_size,
                              hipStream_t stream) {
    const float* x     = (const float*)d_in[0];   // (8,128,80,80)
    const float* w_off = (const float*)d_in[1];   // (18,128,3,3)
    const float* b_off = (const float*)d_in[2];   // (18,)
    const float* wmain = (const float*)d_in[3];   // (128,128,3,3)
    const float* bias  = (const float*)d_in[4];   // (128,)
    float* out = (float*)d_out;                   // (8,128,80,80)

    const size_t offsB_full = 8u * 18u * HWSZ * 4u;        // 3,686,400
    const size_t planeB     = (size_t)PLANE * 2u;          // 2,359,296
    const bool big = ws_size >= (offsB_full + 8 * planeB + 294912 + 73728);

    if (big) {
        // single-pass layout: offs | planes(8) | wA | wAoff  (22.93 MB)
        float*  offs  = (float*)d_ws;
        ushort* xTp   = (ushort*)((char*)d_ws + offsB_full);
        ushort* wA    = (ushort*)((char*)xTp + 8 * planeB);
        ushort* wAoff = (ushort*)((char*)wA + 294912);

        prep_weights<<<720, 256, 0, stream>>>(wmain, w_off, wA, wAoff);
        transpose_x<<<dim3(8, 96), 256, 0, stream>>>(x, xTp, 0);
        offset_mfma<<<dim3(8, 5, 20), 256, 0, stream>>>(xTp, wAoff, b_off, offs);
        deform_gemm<<<dim3(8, 5, 40), 256, 0, stream>>>(xTp, offs, wA, bias, out, 0);
    } else {
        // per-n layout: plane(1) | offs(1) | wA | wAoff  (3.19 MB)
        ushort* xTp   = (ushort*)d_ws;
        float*  offs  = (float*)((char*)d_ws + planeB);
        ushort* wA    = (ushort*)((char*)offs + 18u * HWSZ * 4u);
        ushort* wAoff = (ushort*)((char*)wA + 294912);

        prep_weights<<<720, 256, 0, stream>>>(wmain, w_off, wA, wAoff);
        for (int n = 0; n < 8; ++n) {
            transpose_x<<<dim3(1, 96), 256, 0, stream>>>(x, xTp, n);
            offset_mfma<<<dim3(1, 5, 20), 256, 0, stream>>>(xTp, wAoff, b_off, offs);
            deform_gemm<<<dim3(1, 5, 40), 256, 0, stream>>>(xTp, offs, wA, bias, out, n);
        }
    }
}